// Round 1
// baseline (266.898 us; speedup 1.0000x reference)
//
#include <hip/hip_runtime.h>

// AggFeatureModel: per-row aggregation over T=2048 transactions.
// out[b] = [sl, sum, mean, std,
//           mcc_cnt[100], mcc_mean[100], mcc_std[100],
//           tr_cnt[50],  tr_mean[50],  tr_std[50],
//           distinct_mcc, distinct_tr]   -> 456 cols
// Reference sums over FULL T (seq_lens is only a divisor), cats in [1, C).

#define NCM 100
#define NCT 50
#define NCAT (NCM + NCT)
#define NCOL 456
#define NWAVE 4

static constexpr float EPS = 1e-9f;

__global__ __launch_bounds__(256) void agg_kernel(
    const float* __restrict__ amount,
    const int* __restrict__ mcc,
    const int* __restrict__ tr,
    const int* __restrict__ seq_lens,
    float* __restrict__ out,
    int T)
{
    const int b = blockIdx.x;
    const int tid = threadIdx.x;
    const int wave = tid >> 6;

    // per-wave private bins to cut atomic contention: [wave][stat][cat]
    __shared__ float bins[NWAVE][3][NCAT];
    __shared__ float red[3][NCAT];
    __shared__ float partials[2 * NWAVE];  // s per wave, then ss per wave
    __shared__ float dist[2];

    for (int i = tid; i < NWAVE * 3 * NCAT; i += 256)
        (&bins[0][0][0])[i] = 0.f;
    if (tid < 2) dist[tid] = 0.f;
    __syncthreads();

    const float* arow = amount + (size_t)b * T;
    const int*   mrow = mcc    + (size_t)b * T;
    const int*   trow = tr     + (size_t)b * T;

    float s = 0.f, ss = 0.f;
    float (*mybins)[NCAT] = bins[wave];

    for (int t0 = tid * 4; t0 < T; t0 += 256 * 4) {
        float4 a4 = *reinterpret_cast<const float4*>(arow + t0);
        int4   m4 = *reinterpret_cast<const int4*>(mrow + t0);
        int4   t4 = *reinterpret_cast<const int4*>(trow + t0);
        float av[4] = {a4.x, a4.y, a4.z, a4.w};
        int   mv[4] = {m4.x, m4.y, m4.z, m4.w};
        int   tv[4] = {t4.x, t4.y, t4.z, t4.w};
#pragma unroll
        for (int j = 0; j < 4; ++j) {
            float a  = av[j];
            float aa = a * a;
            s += a; ss += aa;
            int cm = mv[j];          // in [1,100)
            int ct = NCM + tv[j];    // in [101,150)
            atomicAdd(&mybins[0][cm], 1.f);
            atomicAdd(&mybins[1][cm], a);
            atomicAdd(&mybins[2][cm], aa);
            atomicAdd(&mybins[0][ct], 1.f);
            atomicAdd(&mybins[1][ct], a);
            atomicAdd(&mybins[2][ct], aa);
        }
    }

    // wave-level reduce of s, ss
#pragma unroll
    for (int off = 32; off > 0; off >>= 1) {
        s  += __shfl_down(s,  off, 64);
        ss += __shfl_down(ss, off, 64);
    }
    if ((tid & 63) == 0) { partials[wave] = s; partials[NWAVE + wave] = ss; }
    __syncthreads();

    // combine per-wave bins
    for (int i = tid; i < 3 * NCAT; i += 256) {
        int k = i / NCAT, c = i - k * NCAT;
        float v = 0.f;
#pragma unroll
        for (int w = 0; w < NWAVE; ++w) v += bins[w][k][c];
        red[k][c] = v;
    }
    __syncthreads();

    // distinct category counts (e_cnt>0; column 0 is masked out)
    for (int c = tid; c < NCAT; c += 256) {
        bool is_tr = (c >= NCM);
        int  cc    = is_tr ? (c - NCM) : c;
        if (cc > 0 && red[0][c] > 0.f)
            atomicAdd(&dist[is_tr ? 1 : 0], 1.f);
    }

    float s_tot  = partials[0] + partials[1] + partials[2] + partials[3];
    float ss_tot = partials[4] + partials[5] + partials[6] + partials[7];
    float sl = (float)seq_lens[b];
    __syncthreads();  // dist ready

    float* orow = out + (size_t)b * NCOL;
    for (int col = tid; col < NCOL; col += 256) {
        float v;
        if (col == 0)      v = sl;
        else if (col == 1) v = s_tot;
        else if (col == 2) v = s_tot / (sl + EPS);
        else if (col == 3) {
            float a = ss_tot - s_tot * s_tot / (sl + EPS);
            a = fmaxf(a, 0.f);
            v = sqrtf(a / (fmaxf(sl - 1.f, 0.f) + EPS));
        }
        else if (col == 454) v = dist[0];
        else if (col == 455) v = dist[1];
        else {
            int base, C, coff;
            if (col < 304) { base = 4;   C = NCM; coff = 0;   }
            else           { base = 304; C = NCT; coff = NCM; }
            int rel   = col - base;
            int which = rel / C;
            int c     = rel - which * C;
            float cnt = (c > 0) ? red[0][coff + c] : 0.f;  // e_cnt = cnt*mask
            float sc  = red[1][coff + c];
            float ssc = red[2][coff + c];
            if (which == 0)      v = cnt;
            else if (which == 1) v = sc / (cnt + EPS);
            else {
                float a = ssc - sc * sc / (cnt + EPS);
                a = fmaxf(a, 0.f);
                v = sqrtf(a / (fmaxf(cnt - 1.f, 0.f) + EPS));
            }
        }
        orow[col] = v;
    }
}

extern "C" void kernel_launch(void* const* d_in, const int* in_sizes, int n_in,
                              void* d_out, int out_size, void* d_ws, size_t ws_size,
                              hipStream_t stream) {
    const float* amount   = (const float*)d_in[0];
    const int*   mcc      = (const int*)d_in[1];
    const int*   tr_type  = (const int*)d_in[2];
    const int*   seq_lens = (const int*)d_in[3];
    float*       out      = (float*)d_out;

    const int B = in_sizes[3];            // 4096
    const int T = in_sizes[0] / B;        // 2048

    agg_kernel<<<B, 256, 0, stream>>>(amount, mcc, tr_type, seq_lens, out, T);
}

// Round 2
// 172.662 us; speedup vs baseline: 1.5458x; 1.5458x over previous
//
#include <hip/hip_runtime.h>

// AggFeatureModel: per-row aggregation over T=2048 transactions.
// Joint-histogram formulation: accumulate (cnt, sum, sumsq) into a
// 100x50 joint (mcc,tr) LDS table with 3 LDS atomics/element, then
// marginalize to the 100 mcc and 50 tr tables. Halves atomic traffic
// vs separate tables AND nearly eliminates same-address collisions
// (5000 bins vs 100), which was the serialization wall.

#define CM 100
#define CT 50
#define NJ (CM * CT)      // 5000 joint bins
#define NCAT (CM + CT)    // 150 marginal cats
#define NCOL 456

static constexpr float EPS = 1e-9f;

__global__ __launch_bounds__(256) void agg_kernel(
    const float* __restrict__ amount,
    const int* __restrict__ mcc,
    const int* __restrict__ tr,
    const int* __restrict__ seq_lens,
    float* __restrict__ out,
    int T)
{
    const int b = blockIdx.x;
    const int tid = threadIdx.x;
    const int wave = tid >> 6;

    __shared__ float jb[3][NJ];        // 60000 B: [stat][mcc*50+tr]
    __shared__ float red[3][NCAT];     // marginals: [stat][cat] (mcc then tr)
    __shared__ float partials[8];      // s per wave, ss per wave
    __shared__ float dist[2];

    // zero joint bins with float4 writes: 15000 floats = 3750 float4
    {
        float4* p = reinterpret_cast<float4*>(&jb[0][0]);
        const float4 z4 = make_float4(0.f, 0.f, 0.f, 0.f);
        for (int i = tid; i < (3 * NJ) / 4; i += 256) p[i] = z4;
    }
    if (tid < 2) dist[tid] = 0.f;
    __syncthreads();

    const float* arow = amount + (size_t)b * T;
    const int*   mrow = mcc    + (size_t)b * T;
    const int*   trow = tr     + (size_t)b * T;

    float s = 0.f, ss = 0.f;

    for (int t0 = tid * 4; t0 < T; t0 += 256 * 4) {
        float4 a4 = *reinterpret_cast<const float4*>(arow + t0);
        int4   m4 = *reinterpret_cast<const int4*>(mrow + t0);
        int4   t4 = *reinterpret_cast<const int4*>(trow + t0);
        float av[4] = {a4.x, a4.y, a4.z, a4.w};
        int   mv[4] = {m4.x, m4.y, m4.z, m4.w};
        int   tv[4] = {t4.x, t4.y, t4.z, t4.w};
#pragma unroll
        for (int j = 0; j < 4; ++j) {
            float a  = av[j];
            float aa = a * a;
            s += a; ss += aa;
            int key = mv[j] * CT + tv[j];   // mcc in [1,100), tr in [1,50)
            atomicAdd(&jb[0][key], 1.f);
            atomicAdd(&jb[1][key], a);
            atomicAdd(&jb[2][key], aa);
        }
    }

    // wave-level reduce of s, ss
#pragma unroll
    for (int off = 32; off > 0; off >>= 1) {
        s  += __shfl_down(s,  off, 64);
        ss += __shfl_down(ss, off, 64);
    }
    if ((tid & 63) == 0) { partials[wave] = s; partials[4 + wave] = ss; }
    __syncthreads();

    // marginalize joint -> mcc[100] and tr[50] per stat: 450 tasks
    for (int i = tid; i < 3 * NCAT; i += 256) {
        int k = i / NCAT, c = i - k * NCAT;
        float v = 0.f;
        if (c < CM) {                       // mcc cat c: sum over tr
            const float* row = &jb[k][c * CT];
            for (int t = 0; t < CT; ++t) v += row[t];
        } else {                            // tr cat (c-CM): sum over mcc
            int tt = c - CM;
            for (int m = 0; m < CM; ++m) v += jb[k][m * CT + tt];
        }
        red[k][c] = v;
    }
    __syncthreads();

    // distinct category counts (cat 0 masked out)
    for (int c = tid; c < NCAT; c += 256) {
        bool is_tr = (c >= CM);
        int  cc    = is_tr ? (c - CM) : c;
        if (cc > 0 && red[0][c] > 0.f)
            atomicAdd(&dist[is_tr ? 1 : 0], 1.f);
    }

    float s_tot  = partials[0] + partials[1] + partials[2] + partials[3];
    float ss_tot = partials[4] + partials[5] + partials[6] + partials[7];
    float sl = (float)seq_lens[b];
    __syncthreads();  // dist ready

    float* orow = out + (size_t)b * NCOL;
    for (int col = tid; col < NCOL; col += 256) {
        float v;
        if (col == 0)      v = sl;
        else if (col == 1) v = s_tot;
        else if (col == 2) v = s_tot / (sl + EPS);
        else if (col == 3) {
            float a = ss_tot - s_tot * s_tot / (sl + EPS);
            a = fmaxf(a, 0.f);
            v = sqrtf(a / (fmaxf(sl - 1.f, 0.f) + EPS));
        }
        else if (col == 454) v = dist[0];
        else if (col == 455) v = dist[1];
        else {
            int base, C, coff;
            if (col < 304) { base = 4;   C = CM; coff = 0;  }
            else           { base = 304; C = CT; coff = CM; }
            int rel   = col - base;
            int which = rel / C;
            int c     = rel - which * C;
            float cnt = (c > 0) ? red[0][coff + c] : 0.f;  // e_cnt = cnt*mask
            float sc  = red[1][coff + c];
            float ssc = red[2][coff + c];
            if (which == 0)      v = cnt;
            else if (which == 1) v = sc / (cnt + EPS);
            else {
                float a = ssc - sc * sc / (cnt + EPS);
                a = fmaxf(a, 0.f);
                v = sqrtf(a / (fmaxf(cnt - 1.f, 0.f) + EPS));
            }
        }
        orow[col] = v;
    }
}

extern "C" void kernel_launch(void* const* d_in, const int* in_sizes, int n_in,
                              void* d_out, int out_size, void* d_ws, size_t ws_size,
                              hipStream_t stream) {
    const float* amount   = (const float*)d_in[0];
    const int*   mcc      = (const int*)d_in[1];
    const int*   tr_type  = (const int*)d_in[2];
    const int*   seq_lens = (const int*)d_in[3];
    float*       out      = (float*)d_out;

    const int B = in_sizes[3];            // 4096
    const int T = in_sizes[0] / B;        // 2048

    agg_kernel<<<B, 256, 0, stream>>>(amount, mcc, tr_type, seq_lens, out, T);
}

// Round 3
// 151.135 us; speedup vs baseline: 1.7660x; 1.1424x over previous
//
#include <hip/hip_runtime.h>
#include <stdint.h>

// AggFeatureModel via MFMA one-hot matmul. Per row (one wave each):
//   D[160, 16] = OHE[160 cats, T] x B[T, 16]   (cols: 0=1 ->cnt, 1=a ->sum, 2=a^2 ->sumsq)
// cat slots: mcc -> 0..99, tr+100 -> 100..149 (both one-hots live in the same matmul).
// A-frags built in-register by key compares (no LDS one-hot, no atomics, no barriers).
// Scalar row stats (s,ss) kept in exact f32 side accumulators for precision.

#define CM 100
#define NCOL 456
#define MT 10   // 10 m-tiles of 16 = 160 cat slots

static constexpr float EPS = 1e-9f;

typedef __bf16 bf16x8 __attribute__((ext_vector_type(8)));
typedef float  f32x4  __attribute__((ext_vector_type(4)));
typedef unsigned int u32x4 __attribute__((ext_vector_type(4)));

__global__ __launch_bounds__(256, 4) void agg_mfma(
    const float* __restrict__ amount,
    const int* __restrict__ mcc,
    const int* __restrict__ tr,
    const int* __restrict__ seq_lens,
    float* __restrict__ out,
    int T, int B)
{
    const int lane = threadIdx.x & 63;
    const int wave = threadIdx.x >> 6;
    const int row  = blockIdx.x * 4 + wave;
    if (row >= B) return;
    const int n    = lane & 15;   // operand col (stat) index
    const int grp  = lane >> 4;   // k-group

    __shared__ float red[4][3][160];   // per-wave stat table
    float* tbl = &red[wave][0][0];

    const float* arow = amount + (size_t)row * T;
    const int*   mrow = mcc    + (size_t)row * T;
    const int*   trow = tr     + (size_t)row * T;

    f32x4 acc[MT];
#pragma unroll
    for (int i = 0; i < MT; ++i) acc[i] = (f32x4){0.f, 0.f, 0.f, 0.f};

    float s_p = 0.f, ss_p = 0.f;   // exact f32 row sums (16x overcount, fixed later)
    const int nkt = T >> 5;

#pragma unroll 1
    for (int kt = 0; kt < nkt; ++kt) {
        const int kb = (kt << 5) + (grp << 3);
        const float4 a0 = *reinterpret_cast<const float4*>(arow + kb);
        const float4 a1 = *reinterpret_cast<const float4*>(arow + kb + 4);
        const int4   m0 = *reinterpret_cast<const int4*>(mrow + kb);
        const int4   m1 = *reinterpret_cast<const int4*>(mrow + kb + 4);
        const int4   t0 = *reinterpret_cast<const int4*>(trow + kb);
        const int4   t1 = *reinterpret_cast<const int4*>(trow + kb + 4);

        const float av[8] = {a0.x,a0.y,a0.z,a0.w,a1.x,a1.y,a1.z,a1.w};
        const int   k1[8] = {m0.x,m0.y,m0.z,m0.w,m1.x,m1.y,m1.z,m1.w};
        const int   k2[8] = {t0.x+CM,t0.y+CM,t0.z+CM,t0.w+CM,
                             t1.x+CM,t1.y+CM,t1.z+CM,t1.w+CM};

        // pack bf16 pairs (truncation; absolute tolerance is huge) via v_perm
        uint32_t apk[4], qpk[4];
#pragma unroll
        for (int i = 0; i < 4; ++i) {
            float lo = av[2*i], hi = av[2*i+1];
            float lo2 = lo*lo, hi2 = hi*hi;
            apk[i] = __builtin_amdgcn_perm(__float_as_uint(hi),  __float_as_uint(lo),  0x07060302u);
            qpk[i] = __builtin_amdgcn_perm(__float_as_uint(hi2), __float_as_uint(lo2), 0x07060302u);
            s_p  += lo + hi;
            ss_p += lo2 + hi2;
        }

        // B fragment: col n of [K x 16]: n==0 -> 1.0, n==1 -> a, n==2 -> a^2, else 0
        u32x4 bw;
#pragma unroll
        for (int i = 0; i < 4; ++i)
            bw[i] = (n == 0) ? 0x3f803f80u
                  : (n == 1) ? apk[i]
                  : (n == 2) ? qpk[i] : 0u;
        const bf16x8 bf = __builtin_bit_cast(bf16x8, bw);

        // A fragments per m-tile: one-hot(key == m), m = mt*16 + (lane&15)
#pragma unroll
        for (int mt = 0; mt < MT; ++mt) {
            const int m = (mt << 4) + n;
            u32x4 aw;
#pragma unroll
            for (int i = 0; i < 4; ++i) {
                bool c0, c1;
                if (mt <= 5)      { c0 = (k1[2*i] == m);   c1 = (k1[2*i+1] == m); }
                else if (mt >= 7) { c0 = (k2[2*i] == m);   c1 = (k2[2*i+1] == m); }
                else              { c0 = (k1[2*i] == m) || (k2[2*i] == m);
                                    c1 = (k1[2*i+1] == m) || (k2[2*i+1] == m); }
                aw[i] = (c0 ? 0x00003f80u : 0u) | (c1 ? 0x3f800000u : 0u);
            }
            const bf16x8 af = __builtin_bit_cast(bf16x8, aw);
            acc[mt] = __builtin_amdgcn_mfma_f32_16x16x32_bf16(af, bf, acc[mt], 0, 0, 0);
        }
    }

    // ---- epilogue (all per-wave; no __syncthreads anywhere) ----
    // D layout (m89-verified): col = lane&15, row = (lane>>4)*4 + reg
    if (n < 3) {
#pragma unroll
        for (int mt = 0; mt < MT; ++mt)
#pragma unroll
            for (int r = 0; r < 4; ++r)
                tbl[n*160 + (mt<<4) + (grp<<2) + r] = acc[mt][r];
    }
    asm volatile("s_waitcnt lgkmcnt(0)" ::: "memory");

    // wave-reduce exact scalar sums; each element was summed by 16 lanes
#pragma unroll
    for (int off = 32; off; off >>= 1) {
        s_p  += __shfl_xor(s_p,  off, 64);
        ss_p += __shfl_xor(ss_p, off, 64);
    }
    const float s_tot  = s_p  * 0.0625f;
    const float ss_tot = ss_p * 0.0625f;

    // distinct counts via ballot over the (exact-integer) cnt row
    int dm = 0, dt = 0;
    for (int c0 = 0; c0 < 160; c0 += 64) {
        int c = c0 + lane;
        bool pos = (c < 160) && (tbl[c] > 0.f);
        dm += __popcll(__ballot(pos && c >= 1   && c < 100));
        dt += __popcll(__ballot(pos && c >= 101 && c < 150));
    }

    const float sl = (float)seq_lens[row];
    float* orow = out + (size_t)row * NCOL;

    for (int col = lane; col < NCOL; col += 64) {
        float v;
        if (col == 0)      v = sl;
        else if (col == 1) v = s_tot;
        else if (col == 2) v = s_tot / (sl + EPS);
        else if (col == 3) {
            float a = fmaxf(ss_tot - s_tot * s_tot / (sl + EPS), 0.f);
            v = sqrtf(a / (fmaxf(sl - 1.f, 0.f) + EPS));
        }
        else if (col == 454) v = (float)dm;
        else if (col == 455) v = (float)dt;
        else {
            int base, C, soff;
            if (col < 304) { base = 4;   C = 100; soff = 0;   }
            else           { base = 304; C = 50;  soff = 100; }
            int rel   = col - base;
            int which = rel / C;
            int c     = rel - which * C;
            int slot  = soff + c;
            float cnt = (c > 0) ? tbl[slot] : 0.f;   // e_cnt = cnt*mask
            float sc  = tbl[160 + slot];
            float ssc = tbl[320 + slot];
            if (which == 0)      v = cnt;
            else if (which == 1) v = sc / (cnt + EPS);
            else {
                float a = fmaxf(ssc - sc * sc / (cnt + EPS), 0.f);
                v = sqrtf(a / (fmaxf(cnt - 1.f, 0.f) + EPS));
            }
        }
        orow[col] = v;
    }
}

extern "C" void kernel_launch(void* const* d_in, const int* in_sizes, int n_in,
                              void* d_out, int out_size, void* d_ws, size_t ws_size,
                              hipStream_t stream) {
    const float* amount   = (const float*)d_in[0];
    const int*   mcc      = (const int*)d_in[1];
    const int*   tr_type  = (const int*)d_in[2];
    const int*   seq_lens = (const int*)d_in[3];
    float*       out      = (float*)d_out;

    const int B = in_sizes[3];            // 4096
    const int T = in_sizes[0] / B;        // 2048

    const int grid = (B + 3) / 4;         // one wave per row, 4 rows per block
    agg_mfma<<<grid, 256, 0, stream>>>(amount, mcc, tr_type, seq_lens, out, T, B);
}

// Round 4
// 104.308 us; speedup vs baseline: 2.5587x; 1.4489x over previous
//
#include <hip/hip_runtime.h>
#include <stdint.h>

// AggFeatureModel via 2D-factored one-hot MFMA.
// key = 16*t + u. hist[16t+u] = sum_k [t_k==t]([u_k==u]*stat_k)
//   => ONE 16x16x32 MFMA per stat per 32 virtual elements:
//      A[t][k]  = one-hot of high nibble (mcc rows 0..6, tr rows 7..10)
//      B[k][u]  = one-hot of low nibble * stat   (stat in {1, a})
//      sumsq    = (A*a) x (B*a)  -- squares computed BY the MFMA.
// K-slices: grp0: mcc keys of reals 0-7, grp1: mcc of 8-15,
//           grp2: tr  keys of reals 0-7, grp3: tr  of 8-15.
// Per wave: one batch row; no atomics, no __syncthreads.

#define NCOL 456
static constexpr float EPS = 1e-9f;

typedef __bf16 bf16x8 __attribute__((ext_vector_type(8)));
typedef float  f32x4  __attribute__((ext_vector_type(4)));
typedef unsigned int u32x4 __attribute__((ext_vector_type(4)));

__global__ __launch_bounds__(256) void agg2d(
    const float* __restrict__ amount,
    const int* __restrict__ mcc,
    const int* __restrict__ tr,
    const int* __restrict__ seq_lens,
    float* __restrict__ out, int T, int B)
{
    const int lane = threadIdx.x & 63;
    const int wave = threadIdx.x >> 6;
    const int row  = blockIdx.x * 4 + wave;
    if (row >= B) return;
    const int n     = lane & 15;       // A-row / B-col slot for this lane
    const int grp   = lane >> 4;       // k-slice
    const bool istr = (grp >= 2);
    const int nt    = istr ? (n - 7) : n;   // t-compare target (A row = t + 7 for tr)
    const int roff  = (grp & 1) * 8;

    // per-wave stat tables: [stat][176] ; slots 0..111 = mcc (row*16+u), 112..175 = tr
    __shared__ float red[4][3][176];
    float* tbl = &red[wave][0][0];

    const float* pa = amount + (size_t)row * T + roff;
    const int*   pk = (istr ? tr : mcc) + (size_t)row * T + roff;

    f32x4 accC = {0.f,0.f,0.f,0.f};   // count hist
    f32x4 accS = {0.f,0.f,0.f,0.f};   // sum hist
    f32x4 accQ = {0.f,0.f,0.f,0.f};   // sumsq hist

    const int nstep = T >> 4;   // 16 reals per step
#pragma unroll 2
    for (int st = 0; st < nstep; ++st) {
        const int base = st << 4;
        const float4 a0 = *reinterpret_cast<const float4*>(pa + base);
        const float4 a1 = *reinterpret_cast<const float4*>(pa + base + 4);
        const int4   k0 = *reinterpret_cast<const int4*>(pk + base);
        const int4   k1 = *reinterpret_cast<const int4*>(pk + base + 4);

        const float av[8] = {a0.x,a0.y,a0.z,a0.w,a1.x,a1.y,a1.z,a1.w};
        const int   kv[8] = {k0.x,k0.y,k0.z,k0.w,k1.x,k1.y,k1.z,k1.w};

        u32x4 wA1, wAa, wB1, wBa;
#pragma unroll
        for (int i = 0; i < 4; ++i) {
            const int   klo = kv[2*i],   khi = kv[2*i+1];
            const float alo = av[2*i],   ahi = av[2*i+1];
            uint32_t apk;   // [bf16(ahi) : bf16(alo)]
            asm("v_cvt_pk_bf16_f32 %0, %1, %2" : "=v"(apk) : "v"(alo), "v"(ahi));
            const uint32_t um = (((klo & 15) == n) ? 0xffffu : 0u)
                              | (((khi & 15) == n) ? 0xffff0000u : 0u);
            const uint32_t tm = (((klo >> 4) == nt) ? 0xffffu : 0u)
                              | (((khi >> 4) == nt) ? 0xffff0000u : 0u);
            wA1[i] = tm & 0x3f803f80u;   // one-hot(t) * 1.0
            wAa[i] = tm & apk;           // one-hot(t) * a
            wB1[i] = um & 0x3f803f80u;   // one-hot(u) * 1.0
            wBa[i] = um & apk;           // one-hot(u) * a
        }
        const bf16x8 fA1 = __builtin_bit_cast(bf16x8, wA1);
        const bf16x8 fAa = __builtin_bit_cast(bf16x8, wAa);
        const bf16x8 fB1 = __builtin_bit_cast(bf16x8, wB1);
        const bf16x8 fBa = __builtin_bit_cast(bf16x8, wBa);

        accC = __builtin_amdgcn_mfma_f32_16x16x32_bf16(fA1, fB1, accC, 0, 0, 0);
        accS = __builtin_amdgcn_mfma_f32_16x16x32_bf16(fA1, fBa, accS, 0, 0, 0);
        accQ = __builtin_amdgcn_mfma_f32_16x16x32_bf16(fAa, fBa, accQ, 0, 0, 0);
    }

    // ---- epilogue (per-wave only) ----
    // D layout: col = lane&15 (=u), row = grp*4 + reg (=t / 7+t2)
#pragma unroll
    for (int r = 0; r < 4; ++r) {
        const int rr = grp * 4 + r;
        int addr = -1;
        if (rr <= 6)       addr = rr * 16 + n;            // mcc slot = cat
        else if (rr <= 10) addr = 112 + (rr - 7) * 16 + n; // tr slot
        if (addr >= 0) {
            tbl[addr]       = accC[r];
            tbl[176 + addr] = accS[r];
            tbl[352 + addr] = accQ[r];
        }
    }
    asm volatile("s_waitcnt lgkmcnt(0)" ::: "memory");
    __builtin_amdgcn_sched_barrier(0);

    // full-row sum / sumsq from hist rows 0..6 (every element hits exactly one mcc slot)
    float sS = 0.f, sQ = 0.f;
    if (grp == 0) {
        sS = accS[0] + accS[1] + accS[2] + accS[3];
        sQ = accQ[0] + accQ[1] + accQ[2] + accQ[3];
    } else if (grp == 1) {
        sS = accS[0] + accS[1] + accS[2];   // rows 4,5,6 (row 7 = tr)
        sQ = accQ[0] + accQ[1] + accQ[2];
    }
#pragma unroll
    for (int off = 32; off; off >>= 1) {
        sS += __shfl_xor(sS, off, 64);
        sQ += __shfl_xor(sQ, off, 64);
    }
    const float s_tot = sS, ss_tot = sQ;

    // distinct counts via ballot over cnt table (cat 0 masked out)
    int dm = 0, dt = 0;
    for (int c0 = 0; c0 < 160; c0 += 64) {
        const int c = c0 + lane;
        bool pos = false;
        if (c < 100)      pos = (c >= 1)   && (tbl[c] > 0.f);
        else if (c < 150) pos = (c >= 101) && (tbl[112 + (c - 100)] > 0.f);
        dm += __popcll(__ballot(pos && c < 100));
        dt += __popcll(__ballot(pos && c >= 100));
    }

    const float sl = (float)seq_lens[row];
    float* orow = out + (size_t)row * NCOL;

    for (int col = lane; col < NCOL; col += 64) {
        float v;
        if (col == 0)      v = sl;
        else if (col == 1) v = s_tot;
        else if (col == 2) v = s_tot / (sl + EPS);
        else if (col == 3) {
            float a = fmaxf(ss_tot - s_tot * s_tot / (sl + EPS), 0.f);
            v = sqrtf(a / (fmaxf(sl - 1.f, 0.f) + EPS));
        }
        else if (col == 454) v = (float)dm;
        else if (col == 455) v = (float)dt;
        else {
            int base, C, toff;
            if (col < 304) { base = 4;   C = 100; toff = 0;   }
            else           { base = 304; C = 50;  toff = 112; }
            const int rel   = col - base;
            const int which = rel / C;
            const int c     = rel - which * C;
            const float cnt = (c > 0) ? tbl[toff + c] : 0.f;  // e_cnt = cnt*mask
            const float sc  = tbl[176 + toff + c];
            const float ssc = tbl[352 + toff + c];
            if (which == 0)      v = cnt;
            else if (which == 1) v = sc / (cnt + EPS);
            else {
                float a = fmaxf(ssc - sc * sc / (cnt + EPS), 0.f);
                v = sqrtf(a / (fmaxf(cnt - 1.f, 0.f) + EPS));
            }
        }
        orow[col] = v;
    }
}

extern "C" void kernel_launch(void* const* d_in, const int* in_sizes, int n_in,
                              void* d_out, int out_size, void* d_ws, size_t ws_size,
                              hipStream_t stream) {
    const float* amount   = (const float*)d_in[0];
    const int*   mcc      = (const int*)d_in[1];
    const int*   tr_type  = (const int*)d_in[2];
    const int*   seq_lens = (const int*)d_in[3];
    float*       out      = (float*)d_out;

    const int B = in_sizes[3];            // 4096
    const int T = in_sizes[0] / B;        // 2048

    const int grid = (B + 3) / 4;         // one wave per row
    agg2d<<<grid, 256, 0, stream>>>(amount, mcc, tr_type, seq_lens, out, T, B);
}

// Round 6
// 81.544 us; speedup vs baseline: 3.2730x; 1.2792x over previous
//
#include <hip/hip_runtime.h>
#include <stdint.h>

// AggFeatureModel via 2D-factored one-hot MFMA, 2 waves per row.
// key = 16*t + u. hist[16t+u] = sum_k [t_k==t]([u_k==u]*stat_k)
//   A[t][k] = one-hot(t) (mcc rows 0..6, tr rows 7..10)
//   B[k][u] = one-hot(u) * stat (stat in {1, a}); sumsq = (A*a)x(B*a).
// K-slices per wave: grp0/1 = mcc keys of reals 0-7/8-15, grp2/3 = tr same.
// SWAR mask-gen: pack 2 keys as halfwords, one XOR serves u- and t-tests,
// EQ mask per halfword: sign(0x8000 - h) broadcast via COMPILER-generated
// packed ashr (ext_vector short2 >> 15) -- NOT inline asm (r5 failed on
// VOP3P inline-constant op_sel_hi semantics of hand-written v_pk_ashrrev).
// Block = 512 thr = 4 rows x 2 half-row waves -> up to 32 waves/CU.

#define NCOL 456
static constexpr float EPS = 1e-9f;

typedef __bf16 bf16x8 __attribute__((ext_vector_type(8)));
typedef float  f32x4  __attribute__((ext_vector_type(4)));
typedef unsigned int u32x4 __attribute__((ext_vector_type(4)));
typedef short  s16x2  __attribute__((ext_vector_type(2)));

__device__ __forceinline__ uint32_t hw_eqmask(uint32_t h) {
    // h: two halfwords, each in [0,15]; returns 0xFFFF per halfword iff h==0.
    const uint32_t s = 0x80008000u - h;           // sign set iff halfword==0
    const s16x2 m = __builtin_bit_cast(s16x2, s) >> 15;  // packed ashr, compiler-encoded
    return __builtin_bit_cast(uint32_t, m);
}

__global__ __launch_bounds__(512, 8) void agg2d(
    const float* __restrict__ amount,
    const int* __restrict__ mcc,
    const int* __restrict__ tr,
    const int* __restrict__ seq_lens,
    float* __restrict__ out, int T, int B)
{
    const int lane = threadIdx.x & 63;
    const int wv   = threadIdx.x >> 6;   // 0..7
    const int rl   = wv >> 1;            // row within block
    const int half = wv & 1;             // half of the T axis
    const int row  = blockIdx.x * 4 + rl;
    const int n    = lane & 15;          // A-row / B-col slot
    const int grp  = lane >> 4;          // k-slice
    const bool istr = (grp >= 2);
    const int ntc  = istr ? ((n - 7) & 15) : n;   // t-compare target
    const uint32_t xorpat = (uint32_t)(((ntc << 4) | n) * 0x00010001u);
    const int roff = (grp & 1) * 8;

    __shared__ float part[4][2][3][176];  // [row][half][stat][slot]
    __shared__ float scal[4][2][2];       // [row][half][s,ss]

    const int hb = half * (T >> 1);
    const float* pa = amount + (size_t)row * T + hb + roff;
    const int*   pk = (istr ? tr : mcc) + (size_t)row * T + hb + roff;

    f32x4 accC = {0.f,0.f,0.f,0.f};
    f32x4 accS = {0.f,0.f,0.f,0.f};
    f32x4 accQ = {0.f,0.f,0.f,0.f};

    const int nstep = T >> 5;   // (T/2)/16 reals per step
#pragma unroll 2
    for (int st = 0; st < nstep; ++st) {
        const int base = st << 4;
        const float4 a0 = *reinterpret_cast<const float4*>(pa + base);
        const float4 a1 = *reinterpret_cast<const float4*>(pa + base + 4);
        const int4   k0 = *reinterpret_cast<const int4*>(pk + base);
        const int4   k1 = *reinterpret_cast<const int4*>(pk + base + 4);

        const float av[8] = {a0.x,a0.y,a0.z,a0.w,a1.x,a1.y,a1.z,a1.w};
        const uint32_t kv[8] = {(uint32_t)k0.x,(uint32_t)k0.y,(uint32_t)k0.z,(uint32_t)k0.w,
                                (uint32_t)k1.x,(uint32_t)k1.y,(uint32_t)k1.z,(uint32_t)k1.w};

        u32x4 wA1, wAa, wB1, wBa;
#pragma unroll
        for (int i = 0; i < 4; ++i) {
            const uint32_t kpk = __builtin_amdgcn_perm(kv[2*i+1], kv[2*i], 0x05040100u);
            const uint32_t kx  = kpk ^ xorpat;
            const uint32_t mu  = hw_eqmask(kx & 0x000f000fu);         // u-match mask
            const uint32_t mt  = hw_eqmask((kx >> 4) & 0x000f000fu);  // t-match mask
            const uint32_t apk = __builtin_amdgcn_perm(
                __float_as_uint(av[2*i+1]), __float_as_uint(av[2*i]), 0x07060302u);
            wA1[i] = mt & 0x3f803f80u;
            wAa[i] = mt & apk;
            wB1[i] = mu & 0x3f803f80u;
            wBa[i] = mu & apk;
        }
        const bf16x8 fA1 = __builtin_bit_cast(bf16x8, wA1);
        const bf16x8 fAa = __builtin_bit_cast(bf16x8, wAa);
        const bf16x8 fB1 = __builtin_bit_cast(bf16x8, wB1);
        const bf16x8 fBa = __builtin_bit_cast(bf16x8, wBa);

        accC = __builtin_amdgcn_mfma_f32_16x16x32_bf16(fA1, fB1, accC, 0, 0, 0);
        accS = __builtin_amdgcn_mfma_f32_16x16x32_bf16(fA1, fBa, accS, 0, 0, 0);
        accQ = __builtin_amdgcn_mfma_f32_16x16x32_bf16(fAa, fBa, accQ, 0, 0, 0);
    }

    // ---- write per-wave partial tables ----
    // D layout: col = lane&15 (=u), row = grp*4 + reg (=t, or 7+t for tr)
    {
        float* my = &part[rl][half][0][0];
#pragma unroll
        for (int r = 0; r < 4; ++r) {
            const int rr = grp * 4 + r;
            int addr = -1;
            if (rr <= 6)       addr = rr * 16 + n;             // mcc slot
            else if (rr <= 10) addr = 112 + (rr - 7) * 16 + n; // tr slot
            if (addr >= 0) {
                my[addr]       = accC[r];
                my[176 + addr] = accS[r];
                my[352 + addr] = accQ[r];
            }
        }
    }
    // full-row sum/sumsq partials from mcc hist rows (each element hits one mcc slot)
    float sS = 0.f, sQ = 0.f;
    if (grp == 0) {
        sS = accS[0] + accS[1] + accS[2] + accS[3];
        sQ = accQ[0] + accQ[1] + accQ[2] + accQ[3];
    } else if (grp == 1) {
        sS = accS[0] + accS[1] + accS[2];   // rows 4..6 only
        sQ = accQ[0] + accQ[1] + accQ[2];
    }
#pragma unroll
    for (int off = 32; off; off >>= 1) {
        sS += __shfl_xor(sS, off, 64);
        sQ += __shfl_xor(sQ, off, 64);
    }
    if (lane == 0) { scal[rl][half][0] = sS; scal[rl][half][1] = sQ; }
    __syncthreads();

    // ---- combine + write: wave covers cols [half*228, half*228+228) ----
    auto TB = [&](int s, int c) -> float {
        return part[rl][0][s][c] + part[rl][1][s][c];
    };

    int dm = 0, dt = 0;
    if (half) {   // wave-uniform; cols 454/455 live in half1's range
        for (int c0 = 0; c0 < 160; c0 += 64) {
            const int c = c0 + lane;
            bool pos = false;
            if (c >= 1 && c < 100)        pos = TB(0, c) > 0.f;
            else if (c >= 101 && c < 150) pos = TB(0, 112 + (c - 100)) > 0.f;
            dm += __popcll(__ballot(pos && c < 100));
            dt += __popcll(__ballot(pos && c >= 100));
        }
    }

    const float sl     = (float)seq_lens[row];
    const float s_tot  = scal[rl][0][0] + scal[rl][1][0];
    const float ss_tot = scal[rl][0][1] + scal[rl][1][1];
    float* orow = out + (size_t)row * NCOL;

    for (int cc = lane; cc < 228; cc += 64) {
        const int col = half * 228 + cc;
        float v;
        if (col == 0)      v = sl;
        else if (col == 1) v = s_tot;
        else if (col == 2) v = s_tot / (sl + EPS);
        else if (col == 3) {
            float a = fmaxf(ss_tot - s_tot * s_tot / (sl + EPS), 0.f);
            v = sqrtf(a / (fmaxf(sl - 1.f, 0.f) + EPS));
        }
        else if (col == 454) v = (float)dm;
        else if (col == 455) v = (float)dt;
        else {
            int base, C, toff;
            if (col < 304) { base = 4;   C = 100; toff = 0;   }
            else           { base = 304; C = 50;  toff = 112; }
            const int rel   = col - base;
            const int which = rel / C;
            const int c     = rel - which * C;
            const float cnt = (c > 0) ? TB(0, toff + c) : 0.f;  // e_cnt = cnt*mask
            const float sc  = TB(1, toff + c);
            const float ssc = TB(2, toff + c);
            if (which == 0)      v = cnt;
            else if (which == 1) v = sc / (cnt + EPS);
            else {
                float a = fmaxf(ssc - sc * sc / (cnt + EPS), 0.f);
                v = sqrtf(a / (fmaxf(cnt - 1.f, 0.f) + EPS));
            }
        }
        orow[col] = v;
    }
}

extern "C" void kernel_launch(void* const* d_in, const int* in_sizes, int n_in,
                              void* d_out, int out_size, void* d_ws, size_t ws_size,
                              hipStream_t stream) {
    const float* amount   = (const float*)d_in[0];
    const int*   mcc      = (const int*)d_in[1];
    const int*   tr_type  = (const int*)d_in[2];
    const int*   seq_lens = (const int*)d_in[3];
    float*       out      = (float*)d_out;

    const int B = in_sizes[3];            // 4096
    const int T = in_sizes[0] / B;        // 2048

    const int grid = B / 4;               // 4 rows per block, 2 waves per row
    agg2d<<<grid, 512, 0, stream>>>(amount, mcc, tr_type, seq_lens, out, T, B);
}